// Round 19
// baseline (230.167 us; speedup 1.0000x reference)
//
#include <hip/hip_runtime.h>

#define BB 4
#define CC 64
#define SS 2
#define HCC 32
#define AREA_ 16384
#define KDIM 288
#define YPITCH 44
#define CPITCH 72

typedef _Float16 half8 __attribute__((ext_vector_type(8)));
typedef float f32x16 __attribute__((ext_vector_type(16)));

static __device__ __forceinline__ float warp_rsum(float v){
#pragma unroll
  for (int o=32;o>0;o>>=1) v += __shfl_down(v,o,64);
  return v;
}
static __device__ __forceinline__ float warp_rmax(float v){
#pragma unroll
  for (int o=32;o>0;o>>=1) v = fmaxf(v,__shfl_down(v,o,64));
  return v;
}

// ---------- 64x64 1x1 conv as MFMA GEMM ----------
__global__ __launch_bounds__(256,2) void conv_mfma_kernel(const float* __restrict__ in,
    const float* __restrict__ wmat, float* __restrict__ out){
  int b = blockIdx.x >> 7;
  int p0 = (blockIdx.x & 127) << 7;
  __shared__ __align__(16) _Float16 Xp[128*CPITCH];
  int tid = threadIdx.x, lane = tid & 63, wid = tid >> 6;
  int wrow = lane & 31, ko = lane >> 5;

  half8 wf[2][4];
#pragma unroll
  for (int mt=0; mt<2; ++mt)
#pragma unroll
    for (int st=0; st<4; ++st){
      const float* wp = wmat + (size_t)(mt*32+wrow)*64 + st*16 + ko*8;
      float4 a = *(const float4*)wp;
      float4 bq = *(const float4*)(wp+4);
      half8 hv;
      hv[0]=(_Float16)a.x; hv[1]=(_Float16)a.y; hv[2]=(_Float16)a.z; hv[3]=(_Float16)a.w;
      hv[4]=(_Float16)bq.x; hv[5]=(_Float16)bq.y; hv[6]=(_Float16)bq.z; hv[7]=(_Float16)bq.w;
      wf[mt][st] = hv;
    }

  {
    int cg = tid >> 5;
    int px4 = (tid & 31) * 4;
    int g2 = (px4 >> 2) & 3;
#pragma unroll
    for (int cc8=0; cc8<8; ++cc8){
      int c = cc8*8 + cg;
      float4 v = *(const float4*)&in[(size_t)(b*CC + c)*AREA_ + p0 + px4];
      int oct = (c>>3) ^ g2;
      float vv[4] = {v.x, v.y, v.z, v.w};
#pragma unroll
      for (int j=0;j<4;j++)
        Xp[(size_t)(px4+j)*CPITCH + oct*8 + (c&7)] = (_Float16)vv[j];
    }
  }
  __syncthreads();

  int pxl = wid*32 + (lane & 31);
  int g2r = (pxl >> 2) & 3;
  f32x16 acc0 = {}, acc1 = {};
#pragma unroll
  for (int st=0; st<4; ++st){
    int u = st*2 + ko;
    half8 bf = *(const half8*)&Xp[(size_t)pxl*CPITCH + ((u ^ g2r)<<3)];
    acc0 = __builtin_amdgcn_mfma_f32_32x32x16_f16(wf[0][st], bf, acc0, 0,0,0);
    acc1 = __builtin_amdgcn_mfma_f32_32x32x16_f16(wf[1][st], bf, acc1, 0,0,0);
  }
  float* ob = out + (size_t)b*CC*AREA_ + p0 + wid*32 + (lane & 31);
  int rb = 4*ko;
#pragma unroll
  for (int reg=0; reg<16; ++reg){
    int o = (reg&3) + 8*(reg>>2) + rb;
    ob[(size_t)o*AREA_]      = acc0[reg];
    ob[(size_t)(o+32)*AREA_] = acc1[reg];
  }
}

// ---------- BN partial stats ----------
__global__ __launch_bounds__(256) void bn_part_kernel(const float* __restrict__ src,
    float* __restrict__ part){
  int c = blockIdx.x, chunk = blockIdx.y;
  float s1=0.f, s2=0.f;
  for (int b=0;b<BB;b++){
    const float* p = src + ((size_t)b*CC + c)*AREA_ + chunk*2048;
    for (int i=threadIdx.x;i<2048;i+=256){ float v=p[i]; s1+=v; s2+=v*v; }
  }
  __shared__ float red[8];
  float w1 = warp_rsum(s1), w2 = warp_rsum(s2);
  int lane = threadIdx.x & 63, wid = threadIdx.x >> 6;
  if (lane==0){ red[wid]=w1; red[4+wid]=w2; }
  __syncthreads();
  if (threadIdx.x==0){
    atomicAdd(&part[c], red[0]+red[1]+red[2]+red[3]);
    atomicAdd(&part[64+c], red[4]+red[5]+red[6]+red[7]);
  }
}

__global__ __launch_bounds__(256) void bn_apply_relu_kernel(const float* __restrict__ src,
    const float* __restrict__ part, const float* __restrict__ gam,
    const float* __restrict__ bet, float* __restrict__ dst){
  size_t i = (size_t)blockIdx.x*256 + threadIdx.x;
  int c = (int)((i >> 14) & 63);
  const float N = (float)(BB*AREA_);
  float m = part[c]/N;
  float var = part[64+c]/N - m*m;
  float sc = gam[c]*rsqrtf(var + 1e-5f);
  float bi = bet[c] - m*sc;
  float v = fmaf(src[i], sc, bi);
  dst[i] = v > 0.f ? v : 0.f;
}

// ---------- fused BN1-apply + query conv ----------
__global__ __launch_bounds__(256) void bnqq_kernel(const float* __restrict__ ycv,
    const float* __restrict__ part, const float* __restrict__ gam,
    const float* __restrict__ bet, const float* __restrict__ qw,
    float* __restrict__ y, float* __restrict__ qq){
  int b = blockIdx.x >> 7;
  int p0 = (blockIdx.x & 127) << 7;
  __shared__ float tile[64][132];
  __shared__ float wsmT[32][68];
  __shared__ float scs[64], bis[64];
  int tid = threadIdx.x;
  for (int idx = tid; idx < 2048; idx += 256){
    int c = idx & 31, o = idx >> 5;
    wsmT[c][o] = qw[(o>>5)*1024 + (o&31)*32 + c];
  }
  if (tid < 64){
    const float N = (float)(BB*AREA_);
    float m = part[tid]/N;
    float var = part[64+tid]/N - m*m;
    float sc = gam[tid]*rsqrtf(var + 1e-5f);
    scs[tid] = sc;
    bis[tid] = bet[tid] - m*sc;
  }
  __syncthreads();
  const float* inb = ycv + (size_t)b*CC*AREA_ + p0;
  float* yb = y + (size_t)b*CC*AREA_ + p0;
  for (int idx = tid; idx < 8192; idx += 256){
    int c = idx >> 7, pp = idx & 127;
    float v = fmaf(inb[(size_t)c*AREA_ + pp], scs[c], bis[c]);
    v = v > 0.f ? v : 0.f;
    tile[c][pp] = v;
    yb[(size_t)c*AREA_ + pp] = v;
  }
  __syncthreads();
  int px = (tid & 31) * 4;
  int og = tid >> 5;
  int sBase = (og >= 4) ? 32 : 0;
  float4 acc[8];
#pragma unroll
  for (int i=0;i<8;i++) acc[i] = make_float4(0.f,0.f,0.f,0.f);
  for (int c=0;c<32;c++){
    float4 v  = *(const float4*)&tile[sBase+c][px];
    float4 w0 = *(const float4*)&wsmT[c][og*8];
    float4 w1 = *(const float4*)&wsmT[c][og*8+4];
    float wv[8] = {w0.x,w0.y,w0.z,w0.w,w1.x,w1.y,w1.z,w1.w};
#pragma unroll
    for (int i=0;i<8;i++){
      acc[i].x = fmaf(wv[i], v.x, acc[i].x);
      acc[i].y = fmaf(wv[i], v.y, acc[i].y);
      acc[i].z = fmaf(wv[i], v.z, acc[i].z);
      acc[i].w = fmaf(wv[i], v.w, acc[i].w);
    }
  }
#pragma unroll
  for (int i=0;i<8;i++){
    int o = og*8 + i;
    int s = o >> 5, oc = o & 31;
    float* ob = qq + (((size_t)(b*SS+s)*HCC + oc)*AREA_) + p0 + px;
    *(float4*)ob = acc[i];
  }
}

// ---------- MFMA gram: atomic accumulation directly into P ----------
__global__ __launch_bounds__(512) void gram_kernel(const float* __restrict__ y,
    const float* __restrict__ qq, float* __restrict__ P){
  const int PAarr[6]={0,0,1,0,1,2}, PBarr[6]={0,1,1,2,2,2};
  const int pairOrder[6]={1,3,4,0,2,5};
  int bid = blockIdx.x;
  int bs = bid & 7;
  int sidx = bid >> 3;
  int pair = pairOrder[sidx >> 4];
  int slotIdx = sidx & 15;
  int Kstart = slotIdx << 10;
  const int nch = 16;
  int PA = PAarr[pair], PB = PBarr[pair];
  int RA = PA<2?128:64, CB = PB<2?128:64;
  bool diag = (PA==PB);
  int rows_tot = RA + (diag?0:CB);
  int passes = rows_tot >> 6;
  int s = bs & 1, b = bs >> 1, dil = 1+s;
  const float* yb = y + ((size_t)b*CC + s*HCC)*AREA_;
  const float* qqb = qq + (size_t)bs*HCC*AREA_;
  __shared__ __align__(16) _Float16 Us[256*64];
  int tid = threadIdx.x;
  int hq = tid & 7, rr8 = tid >> 3;
  int lane = tid & 63, wid = tid >> 6;
  int rbase = (wid>>2)*64, cbase = (wid&3)*32;
  bool active = (rbase < RA) && (cbase < CB);
  int boff = diag ? 0 : RA;
  int r0 = rbase + (lane&31), r1 = r0+32;
  int cr = boff + cbase + (lane&31);
  int uo = lane>>5;

  auto loadPass = [&](int t, int p)->half8{
    int k0 = Kstart + t*64;
    int w = k0>>7, h = (k0&127) + hq*8;
    int pr = p*64 + rr8;
    int pan, prow;
    if (pr < RA){ pan = PA; prow = pr; } else { pan = PB; prow = pr - RA; }
    float vv[8];
    if (pan < 2){
      int l = pan*4 + (prow>>5), ch = prow & 31;
      int oy = ((0x6A40 >> (2*l)) & 3) - 1;
      int ox = ((0x6A4  >> (2*l)) & 3) - 1;
      const float* crow = yb + (size_t)ch*AREA_ + w*128 + h;
      float4 ca = *(const float4*)crow;
      float4 cb = *(const float4*)(crow+4);
      float cen[8] = {ca.x,ca.y,ca.z,ca.w,cb.x,cb.y,cb.z,cb.w};
      float nb[8];
      int wy = w + oy*dil, oxd = ox*dil, hb = h + oxd;
      if (wy>=0 && wy<128){
        const float* nrow = yb + (size_t)ch*AREA_ + wy*128 + hb;
        if (hb>=0 && hb<=120){
          float4 na, nc;
          __builtin_memcpy(&na, nrow, 16);
          __builtin_memcpy(&nc, nrow+4, 16);
          nb[0]=na.x; nb[1]=na.y; nb[2]=na.z; nb[3]=na.w;
          nb[4]=nc.x; nb[5]=nc.y; nb[6]=nc.z; nb[7]=nc.w;
        } else {
#pragma unroll
          for (int j=0;j<8;j++){
            int hx = hb + j;
            nb[j] = (hx>=0 && hx<128) ? nrow[j] : 0.f;
          }
        }
      } else {
#pragma unroll
        for (int j=0;j<8;j++) nb[j]=0.f;
      }
#pragma unroll
      for (int j=0;j<8;j++) vv[j] = cen[j]-nb[j];
    } else {
      const float* src = (prow<32) ? yb + (size_t)prow*AREA_ : qqb + (size_t)(prow-32)*AREA_;
      const float* crow = src + w*128 + h;
      float4 ca = *(const float4*)crow;
      float4 cb = *(const float4*)(crow+4);
      vv[0]=ca.x; vv[1]=ca.y; vv[2]=ca.z; vv[3]=ca.w;
      vv[4]=cb.x; vv[5]=cb.y; vv[6]=cb.z; vv[7]=cb.w;
    }
    half8 hv;
#pragma unroll
    for (int j=0;j<8;j++) hv[j] = (_Float16)vv[j];
    return hv;
  };
  auto writeLDS = [&](int p, half8 hv){
    int pr = p*64 + rr8;
    *(half8*)&Us[(size_t)pr*64 + ((hq ^ (pr&7))<<3)] = hv;
  };

  bool p2 = (passes >= 2), p3 = (passes >= 3), p4 = (passes >= 4);
  half8 f0{}, f1{}, f2{}, f3{};

  f32x16 acc0={}, acc1={};
  f0 = loadPass(0,0);
  if (p2) f1 = loadPass(0,1);
  if (p3) f2 = loadPass(0,2);
  if (p4) f3 = loadPass(0,3);
  for (int t=0; t<nch; ++t){
    asm volatile("s_waitcnt lgkmcnt(0)" ::: "memory");
    __builtin_amdgcn_s_barrier();
    writeLDS(0,f0);
    if (p2) writeLDS(1,f1);
    if (p3) writeLDS(2,f2);
    if (p4) writeLDS(3,f3);
    if (t+1 < nch){
      f0 = loadPass(t+1,0);
      if (p2) f1 = loadPass(t+1,1);
      if (p3) f2 = loadPass(t+1,2);
      if (p4) f3 = loadPass(t+1,3);
    }
    asm volatile("s_waitcnt lgkmcnt(0)" ::: "memory");
    __builtin_amdgcn_s_barrier();
    if (active){
#pragma unroll
      for (int st=0; st<4; ++st){
        int u = st*2 + uo;
        half8 a0 = *(const half8*)&Us[(size_t)r0*64 + ((u^(r0&7))<<3)];
        half8 a1 = *(const half8*)&Us[(size_t)r1*64 + ((u^(r1&7))<<3)];
        half8 bb = *(const half8*)&Us[(size_t)cr*64 + ((u^(cr&7))<<3)];
        acc0 = __builtin_amdgcn_mfma_f32_32x32x16_f16(a0,bb,acc0,0,0,0);
        acc1 = __builtin_amdgcn_mfma_f32_32x32x16_f16(a1,bb,acc1,0,0,0);
      }
    }
  }
  if (active){
    float* Pb = P + (size_t)bs*102400;
    int Roff = PA*128 + rbase, Coff = PB*128 + cbase;
    int rr = 4*uo, cc = lane&31;
#pragma unroll
    for (int reg=0;reg<16;reg++){
      int ro = (reg&3) + 8*(reg>>2) + rr;
      atomicAdd(&Pb[(size_t)(Roff+ro)*320 + Coff+cc],    acc0[reg]);
      atomicAdd(&Pb[(size_t)(Roff+32+ro)*320 + Coff+cc], acc1[reg]);
    }
  }
}

// ---------- symmetrize: fill lower triangle ----------
__global__ __launch_bounds__(256) void symmetrize_kernel(float* __restrict__ P){
  int idx = blockIdx.x*256 + threadIdx.x;
  if (idx >= 320*320) return;
  int r = idx/320, c = idx - r*320;
  float* Pb = P + (size_t)blockIdx.y*102400;
  if (r > c) Pb[idx] = Pb[(size_t)c*320 + r];
}

// ---------- kw transpose ----------
__global__ __launch_bounds__(256) void kwT_kernel(const float* __restrict__ kw, float* __restrict__ kwT){
  int idx = blockIdx.x*256 + threadIdx.x;
  if (idx >= 2*KDIM*KDIM) return;
  int s = idx / (KDIM*KDIM);
  int r = idx - s*KDIM*KDIM;
  int k = r / KDIM, j = r - k*KDIM;
  kwT[(size_t)s*KDIM*KDIM + (size_t)j*KDIM + k] = kw[idx];
}

// ---------- fused V row + key-norm accumulation ----------
__global__ __launch_bounds__(256) void vknorm_kernel(const float* __restrict__ P,
    const float* __restrict__ kwT, float* __restrict__ kn){
  int j = blockIdx.x, bs = blockIdx.y;
  int s = bs & 1;
  __shared__ float prow[KDIM];
  const float* Pb = P + (size_t)bs*102400 + (size_t)j*320;
  for (int i=threadIdx.x;i<KDIM;i+=256) prow[i]=Pb[i];
  __syncthreads();
  const float* kt = kwT + (size_t)s*KDIM*KDIM;
  int k = threadIdx.x;
  float acc=0.f;
  for (int jp=0;jp<KDIM;jp++) acc = fmaf(prow[jp], kt[(size_t)jp*KDIM + k], acc);
  atomicAdd(&kn[bs*256 + k], kt[(size_t)j*KDIM + k] * acc);
}

// ---------- w row + inorm partial stats ----------
__global__ __launch_bounds__(256) void wmat_kernel(const float* __restrict__ P,
    const float* __restrict__ kwT, const float* __restrict__ kn,
    float* __restrict__ wbuf, float* __restrict__ wstats){
  int bs = blockIdx.x >> 5, c = blockIdx.x & 31;
  int s = bs & 1;
  __shared__ float prow[KDIM];
  const float* PbB = P + (size_t)bs*102400;
  const float* Pb = PbB + (size_t)(288+c)*320;
  for (int i=threadIdx.x;i<KDIM;i+=256) prow[i]=Pb[i];
  __syncthreads();
  const float* kt = kwT + (size_t)s*KDIM*KDIM;
  int k = threadIdx.x;
  float acc=0.f;
  for (int j=0;j<KDIM;j++) acc = fmaf(prow[j], kt[(size_t)j*KDIM + k], acc);
  float rk = 1.f/fmaxf(sqrtf(fmaxf(kn[bs*256+k],0.f)),1e-12f);
  float qn = PbB[(size_t)(288+c)*320 + 288+c];
  float rq = 1.f/fmaxf(sqrtf(fmaxf(qn,0.f)),1e-12f);
  float wv = acc * rq * rk * (1.f/128.f);
  wbuf[((size_t)bs*32 + c)*256 + k] = wv;
  __shared__ float red[8];
  float r1 = warp_rsum(wv), r2 = warp_rsum(wv*wv);
  int lane = threadIdx.x & 63, wid = threadIdx.x >> 6;
  if (lane==0){ red[wid]=r1; red[4+wid]=r2; }
  __syncthreads();
  if (threadIdx.x==0){
    atomicAdd(&wstats[bs*2],   red[0]+red[1]+red[2]+red[3]);
    atomicAdd(&wstats[bs*2+1], red[4]+red[5]+red[6]+red[7]);
  }
}

// ---------- inorm + softmax + tap-fragment pack ----------
__global__ __launch_bounds__(256) void smxtswf_kernel(const float* __restrict__ wbuf,
    const float* __restrict__ wstats, _Float16* __restrict__ tswf){
  int bs = blockIdx.x >> 5, c = blockIdx.x & 31;
  float s1 = wstats[bs*2], s2 = wstats[bs*2+1];
  const float N = 8192.f;
  float m = s1/N, var = s2/N - m*m;
  float rs = rsqrtf(var + 1e-5f);
  int k = threadIdx.x;
  float v = (wbuf[((size_t)bs*32 + c)*256 + k] - m)*rs;
  __shared__ float red[4];
  __shared__ float sm[256];
  __shared__ float cs[32];
  float mx = warp_rmax(v);
  int lane = k & 63, wid = k >> 6;
  if (lane==0) red[wid]=mx;
  __syncthreads();
  float MX = fmaxf(fmaxf(red[0],red[1]),fmaxf(red[2],red[3]));
  __syncthreads();
  float e = expf(v - MX);
  float es = warp_rsum(e);
  if (lane==0) red[wid]=es;
  __syncthreads();
  float ES = red[0]+red[1]+red[2]+red[3];
  sm[k] = e/ES;
  __syncthreads();
  if (k < 32){
    float a = 0.f;
#pragma unroll
    for (int l=0;l<8;l++) a += sm[l*32+k];
    cs[k] = a;
  }
  __syncthreads();
  if (k < 36){
    int ks = k >> 1;
    int hi = k & 1;
    int ln = c + (hi<<5);
    half8 hv;
#pragma unroll
    for (int j=0;j<8;j++){
      int ki = ks*16 + (hi<<3) + j;
      int t = ki >> 5, ch = ki & 31;
      float vv = (t==0) ? cs[ch] : -sm[(t-1)*32 + ch];
      hv[j] = (_Float16)vv;
    }
    *(half8*)&tswf[((size_t)(bs*18 + ks)*64 + ln)*8] = hv;
  }
}

// ---------- attention apply as MFMA GEMM ----------
__global__ __launch_bounds__(256,2) void attn_mfma_kernel(const float* __restrict__ y,
    const _Float16* __restrict__ tswf, float* __restrict__ outs){
  int blk = blockIdx.x;
  int w = blk & 127;
  int s = (blk >> 7) & 1;
  int b = blk >> 8;
  int bs = b*SS + s;
  int dil = 1 + s;
  __shared__ __align__(16) _Float16 ybuf[3*132*YPITCH];
  const float* yb = y + ((size_t)bs*HCC)*AREA_;
  int tid = threadIdx.x;
  int lane = tid & 63, wid = tid >> 6;

  const _Float16* tf = tswf + ((size_t)bs*18*64 + lane)*8;
  half8 afr[18];
#pragma unroll
  for (int ks=0; ks<18; ++ks) afr[ks] = *(const half8*)&tf[(size_t)ks*64*8];

  for (int i = tid; i < 384; i += 256){
    int ch = i & 31;
    int q = i >> 5;
    int wr = q >> 2, hb = q & 3;
    int hi = (hb < 2) ? hb : (128 + hb);
    int oct = (ch>>3) ^ ((hi>>2)&3);
    ybuf[(size_t)(wr*132+hi)*YPITCH + oct*8 + (ch&7)] = (_Float16)0.f;
  }
  int ch8 = tid >> 5;
  int h4 = (tid & 31) * 4;
#pragma unroll
  for (int r = 0; r < 12; ++r){
    int wr = r >> 2, chg = r & 3;
    int wy = w + (wr-1)*dil;
    if (wy < 0 || wy >= 128) continue;
    int ch = chg*8 + ch8;
    float4 v = *(const float4*)&yb[(size_t)ch*AREA_ + wy*128 + h4];
    float vv[4] = {v.x, v.y, v.z, v.w};
#pragma unroll
    for (int j=0;j<4;j++){
      int hi = h4 + 2 + j;
      int oct = (ch>>3) ^ ((hi>>2)&3);
      ybuf[(size_t)(wr*132+hi)*YPITCH + oct*8 + (ch&7)] = (_Float16)vv[j];
    }
  }
  __syncthreads();

  const int offy[9]={0,-1,-1,-1,0,1,1,1,0};
  const int offx[9]={0,-1,0,1,1,1,0,-1,-1};
  int n0 = wid * 32;
  int nl = n0 + (lane & 31);
  int ko = lane >> 5;
  f32x16 acc = {};
#pragma unroll
  for (int ks=0; ks<18; ++ks){
    int t = ks >> 1;
    int wy = w + offy[t]*dil;
    half8 bfr = {};
    if (wy >= 0 && wy < 128){
      int wr = offy[t] + 1;
      int hi = nl + offx[t]*dil + 2;
      int oct = (((ks&1)<<1) | ko) ^ ((hi>>2)&3);
      bfr = *(const half8*)&ybuf[(size_t)(wr*132+hi)*YPITCH + oct*8];
    }
    acc = __builtin_amdgcn_mfma_f32_32x32x16_f16(afr[ks], bfr, acc, 0,0,0);
  }
  float* ob = outs + (size_t)bs*HCC*AREA_ + (size_t)w*128;
  int col = n0 + (lane & 31);
  int rb = 4*(lane>>5);
#pragma unroll
  for (int reg=0; reg<16; ++reg){
    int c = (reg&3) + 8*(reg>>2) + rb;
    ob[(size_t)c*AREA_ + col] = acc[reg];
  }
}

extern "C" void kernel_launch(void* const* d_in, const int* in_sizes, int n_in,
                              void* d_out, int out_size, void* d_ws, size_t ws_size,
                              hipStream_t stream){
  const float* x   = (const float*)d_in[0];
  const float* tw  = (const float*)d_in[1];
  const float* g1  = (const float*)d_in[2];
  const float* b1  = (const float*)d_in[3];
  const float* qw  = (const float*)d_in[4];
  const float* kw  = (const float*)d_in[5];
  const float* ow  = (const float*)d_in[6];
  const float* g2  = (const float*)d_in[7];
  const float* b2  = (const float*)d_in[8];
  float* out = (float*)d_out;
  float* ws = (float*)d_ws;

  float* y      = ws + 64;
  float* qqb    = ws + 4194368;
  float* kwT    = qqb;
  float* wbuf   = ws + 4360256;
  float* outs   = ws + 8388672;
  float* P      = ws + 13107264;
  float* stats  = ws + 13926464;
  float* wstats = ws + 13926720;
  float* kn     = ws + 13926976;
  _Float16* tswf = (_Float16*)(ws + 13994816);
  float* z      = y;

  hipMemsetAsync(stats, 0, 2560*sizeof(float), stream);
  hipMemsetAsync(P, 0, (size_t)819200*sizeof(float), stream);

  conv_mfma_kernel<<<512,256,0,stream>>>(x, tw, y);
  bn_part_kernel<<<dim3(64,8),256,0,stream>>>(y, stats);
  bnqq_kernel<<<512,256,0,stream>>>(y, stats, g1, b1, qw, y, qqb);
  gram_kernel<<<768,512,0,stream>>>(y, qqb, P);
  symmetrize_kernel<<<dim3(400,8),256,0,stream>>>(P);
  kwT_kernel<<<648,256,0,stream>>>(kw, kwT);
  vknorm_kernel<<<dim3(288,8),256,0,stream>>>(P, kwT, kn);
  wmat_kernel<<<256,256,0,stream>>>(P, kwT, kn, wbuf, wstats);
  smxtswf_kernel<<<256,256,0,stream>>>(wbuf, wstats, tswf);
  attn_mfma_kernel<<<1024,256,0,stream>>>(y, tswf, outs);
  conv_mfma_kernel<<<512,256,0,stream>>>(outs, ow, z);
  bn_part_kernel<<<dim3(64,8),256,0,stream>>>(z, stats+128);
  bn_apply_relu_kernel<<<16384,256,0,stream>>>(z, stats+128, g2, b2, out);
}

// Round 20
// 224.242 us; speedup vs baseline: 1.0264x; 1.0264x over previous
//
#include <hip/hip_runtime.h>

#define BB 4
#define CC 64
#define SS 2
#define HCC 32
#define AREA_ 16384
#define KDIM 288
#define YPITCH 44
#define CPITCH 72

typedef _Float16 half8 __attribute__((ext_vector_type(8)));
typedef float f32x16 __attribute__((ext_vector_type(16)));

static __device__ __forceinline__ float warp_rsum(float v){
#pragma unroll
  for (int o=32;o>0;o>>=1) v += __shfl_down(v,o,64);
  return v;
}
static __device__ __forceinline__ float warp_rmax(float v){
#pragma unroll
  for (int o=32;o>0;o>>=1) v = fmaxf(v,__shfl_down(v,o,64));
  return v;
}

// ---------- 64x64 1x1 conv as MFMA GEMM ----------
__global__ __launch_bounds__(256,2) void conv_mfma_kernel(const float* __restrict__ in,
    const float* __restrict__ wmat, float* __restrict__ out){
  int b = blockIdx.x >> 7;
  int p0 = (blockIdx.x & 127) << 7;
  __shared__ __align__(16) _Float16 Xp[128*CPITCH];
  int tid = threadIdx.x, lane = tid & 63, wid = tid >> 6;
  int wrow = lane & 31, ko = lane >> 5;

  half8 wf[2][4];
#pragma unroll
  for (int mt=0; mt<2; ++mt)
#pragma unroll
    for (int st=0; st<4; ++st){
      const float* wp = wmat + (size_t)(mt*32+wrow)*64 + st*16 + ko*8;
      float4 a = *(const float4*)wp;
      float4 bq = *(const float4*)(wp+4);
      half8 hv;
      hv[0]=(_Float16)a.x; hv[1]=(_Float16)a.y; hv[2]=(_Float16)a.z; hv[3]=(_Float16)a.w;
      hv[4]=(_Float16)bq.x; hv[5]=(_Float16)bq.y; hv[6]=(_Float16)bq.z; hv[7]=(_Float16)bq.w;
      wf[mt][st] = hv;
    }

  {
    int cg = tid >> 5;
    int px4 = (tid & 31) * 4;
    int g2 = (px4 >> 2) & 3;
#pragma unroll
    for (int cc8=0; cc8<8; ++cc8){
      int c = cc8*8 + cg;
      float4 v = *(const float4*)&in[(size_t)(b*CC + c)*AREA_ + p0 + px4];
      int oct = (c>>3) ^ g2;
      float vv[4] = {v.x, v.y, v.z, v.w};
#pragma unroll
      for (int j=0;j<4;j++)
        Xp[(size_t)(px4+j)*CPITCH + oct*8 + (c&7)] = (_Float16)vv[j];
    }
  }
  __syncthreads();

  int pxl = wid*32 + (lane & 31);
  int g2r = (pxl >> 2) & 3;
  f32x16 acc0 = {}, acc1 = {};
#pragma unroll
  for (int st=0; st<4; ++st){
    int u = st*2 + ko;
    half8 bf = *(const half8*)&Xp[(size_t)pxl*CPITCH + ((u ^ g2r)<<3)];
    acc0 = __builtin_amdgcn_mfma_f32_32x32x16_f16(wf[0][st], bf, acc0, 0,0,0);
    acc1 = __builtin_amdgcn_mfma_f32_32x32x16_f16(wf[1][st], bf, acc1, 0,0,0);
  }
  float* ob = out + (size_t)b*CC*AREA_ + p0 + wid*32 + (lane & 31);
  int rb = 4*ko;
#pragma unroll
  for (int reg=0; reg<16; ++reg){
    int o = (reg&3) + 8*(reg>>2) + rb;
    ob[(size_t)o*AREA_]      = acc0[reg];
    ob[(size_t)(o+32)*AREA_] = acc1[reg];
  }
}

// ---------- BN partial stats ----------
__global__ __launch_bounds__(256) void bn_part_kernel(const float* __restrict__ src,
    float* __restrict__ part){
  int c = blockIdx.x, chunk = blockIdx.y;
  float s1=0.f, s2=0.f;
  for (int b=0;b<BB;b++){
    const float* p = src + ((size_t)b*CC + c)*AREA_ + chunk*2048;
    for (int i=threadIdx.x;i<2048;i+=256){ float v=p[i]; s1+=v; s2+=v*v; }
  }
  __shared__ float red[8];
  float w1 = warp_rsum(s1), w2 = warp_rsum(s2);
  int lane = threadIdx.x & 63, wid = threadIdx.x >> 6;
  if (lane==0){ red[wid]=w1; red[4+wid]=w2; }
  __syncthreads();
  if (threadIdx.x==0){
    atomicAdd(&part[c], red[0]+red[1]+red[2]+red[3]);
    atomicAdd(&part[64+c], red[4]+red[5]+red[6]+red[7]);
  }
}

__global__ __launch_bounds__(256) void bn_apply_relu_kernel(const float* __restrict__ src,
    const float* __restrict__ part, const float* __restrict__ gam,
    const float* __restrict__ bet, float* __restrict__ dst){
  size_t i = (size_t)blockIdx.x*256 + threadIdx.x;
  int c = (int)((i >> 14) & 63);
  const float N = (float)(BB*AREA_);
  float m = part[c]/N;
  float var = part[64+c]/N - m*m;
  float sc = gam[c]*rsqrtf(var + 1e-5f);
  float bi = bet[c] - m*sc;
  float v = fmaf(src[i], sc, bi);
  dst[i] = v > 0.f ? v : 0.f;
}

// ---------- fused BN1-apply + query conv ----------
__global__ __launch_bounds__(256) void bnqq_kernel(const float* __restrict__ ycv,
    const float* __restrict__ part, const float* __restrict__ gam,
    const float* __restrict__ bet, const float* __restrict__ qw,
    float* __restrict__ y, float* __restrict__ qq){
  int b = blockIdx.x >> 7;
  int p0 = (blockIdx.x & 127) << 7;
  __shared__ float tile[64][132];
  __shared__ float wsmT[32][68];
  __shared__ float scs[64], bis[64];
  int tid = threadIdx.x;
  for (int idx = tid; idx < 2048; idx += 256){
    int c = idx & 31, o = idx >> 5;
    wsmT[c][o] = qw[(o>>5)*1024 + (o&31)*32 + c];
  }
  if (tid < 64){
    const float N = (float)(BB*AREA_);
    float m = part[tid]/N;
    float var = part[64+tid]/N - m*m;
    float sc = gam[tid]*rsqrtf(var + 1e-5f);
    scs[tid] = sc;
    bis[tid] = bet[tid] - m*sc;
  }
  __syncthreads();
  const float* inb = ycv + (size_t)b*CC*AREA_ + p0;
  float* yb = y + (size_t)b*CC*AREA_ + p0;
  for (int idx = tid; idx < 8192; idx += 256){
    int c = idx >> 7, pp = idx & 127;
    float v = fmaf(inb[(size_t)c*AREA_ + pp], scs[c], bis[c]);
    v = v > 0.f ? v : 0.f;
    tile[c][pp] = v;
    yb[(size_t)c*AREA_ + pp] = v;
  }
  __syncthreads();
  int px = (tid & 31) * 4;
  int og = tid >> 5;
  int sBase = (og >= 4) ? 32 : 0;
  float4 acc[8];
#pragma unroll
  for (int i=0;i<8;i++) acc[i] = make_float4(0.f,0.f,0.f,0.f);
  for (int c=0;c<32;c++){
    float4 v  = *(const float4*)&tile[sBase+c][px];
    float4 w0 = *(const float4*)&wsmT[c][og*8];
    float4 w1 = *(const float4*)&wsmT[c][og*8+4];
    float wv[8] = {w0.x,w0.y,w0.z,w0.w,w1.x,w1.y,w1.z,w1.w};
#pragma unroll
    for (int i=0;i<8;i++){
      acc[i].x = fmaf(wv[i], v.x, acc[i].x);
      acc[i].y = fmaf(wv[i], v.y, acc[i].y);
      acc[i].z = fmaf(wv[i], v.z, acc[i].z);
      acc[i].w = fmaf(wv[i], v.w, acc[i].w);
    }
  }
#pragma unroll
  for (int i=0;i<8;i++){
    int o = og*8 + i;
    int s = o >> 5, oc = o & 31;
    float* ob = qq + (((size_t)(b*SS+s)*HCC + oc)*AREA_) + p0 + px;
    *(float4*)ob = acc[i];
  }
}

// ---------- MFMA gram: 512 threads / 8 waves, XCD-pinned, single-depth prefetch ----------
__global__ __launch_bounds__(512) void gram_kernel(const float* __restrict__ y,
    const float* __restrict__ qq, float* __restrict__ dpart, float* __restrict__ wpart){
  const int PAarr[6]={0,0,1,0,1,2}, PBarr[6]={0,1,1,2,2,2};
  const int pairOrder[6]={1,3,4,0,2,5};
  const int pairbase[6]={0,262144,524288,786432,917504,1048576};
  const int tsz[6]={16384,16384,16384,8192,8192,4096};
  int bid = blockIdx.x;
  int bs = bid & 7;
  int sidx = bid >> 3;
  int pair = pairOrder[sidx >> 4];
  int slotIdx = sidx & 15;
  int Kstart = slotIdx << 10;
  const int nch = 16;
  int PA = PAarr[pair], PB = PBarr[pair];
  int RA = PA<2?128:64, CB = PB<2?128:64;
  bool diag = (PA==PB);
  int rows_tot = RA + (diag?0:CB);
  int passes = rows_tot >> 6;
  int s = bs & 1, b = bs >> 1, dil = 1+s;
  const float* yb = y + ((size_t)b*CC + s*HCC)*AREA_;
  const float* qqb = qq + (size_t)bs*HCC*AREA_;
  __shared__ __align__(16) _Float16 Us[256*64];
  int tid = threadIdx.x;
  int hq = tid & 7, rr8 = tid >> 3;
  int lane = tid & 63, wid = tid >> 6;
  int rbase = (wid>>2)*64, cbase = (wid&3)*32;
  bool active = (rbase < RA) && (cbase < CB);
  int boff = diag ? 0 : RA;
  int r0 = rbase + (lane&31), r1 = r0+32;
  int cr = boff + cbase + (lane&31);
  int uo = lane>>5;

  auto loadPass = [&](int t, int p)->half8{
    int k0 = Kstart + t*64;
    int w = k0>>7, h = (k0&127) + hq*8;
    int pr = p*64 + rr8;
    int pan, prow;
    if (pr < RA){ pan = PA; prow = pr; } else { pan = PB; prow = pr - RA; }
    float vv[8];
    if (pan < 2){
      int l = pan*4 + (prow>>5), ch = prow & 31;
      int oy = ((0x6A40 >> (2*l)) & 3) - 1;
      int ox = ((0x6A4  >> (2*l)) & 3) - 1;
      const float* crow = yb + (size_t)ch*AREA_ + w*128 + h;
      float4 ca = *(const float4*)crow;
      float4 cb = *(const float4*)(crow+4);
      float cen[8] = {ca.x,ca.y,ca.z,ca.w,cb.x,cb.y,cb.z,cb.w};
      float nb[8];
      int wy = w + oy*dil, oxd = ox*dil, hb = h + oxd;
      if (wy>=0 && wy<128){
        const float* nrow = yb + (size_t)ch*AREA_ + wy*128 + hb;
        if (hb>=0 && hb<=120){
          float4 na, nc;
          __builtin_memcpy(&na, nrow, 16);
          __builtin_memcpy(&nc, nrow+4, 16);
          nb[0]=na.x; nb[1]=na.y; nb[2]=na.z; nb[3]=na.w;
          nb[4]=nc.x; nb[5]=nc.y; nb[6]=nc.z; nb[7]=nc.w;
        } else {
#pragma unroll
          for (int j=0;j<8;j++){
            int hx = hb + j;
            nb[j] = (hx>=0 && hx<128) ? nrow[j] : 0.f;
          }
        }
      } else {
#pragma unroll
        for (int j=0;j<8;j++) nb[j]=0.f;
      }
#pragma unroll
      for (int j=0;j<8;j++) vv[j] = cen[j]-nb[j];
    } else {
      const float* src = (prow<32) ? yb + (size_t)prow*AREA_ : qqb + (size_t)(prow-32)*AREA_;
      const float* crow = src + w*128 + h;
      float4 ca = *(const float4*)crow;
      float4 cb = *(const float4*)(crow+4);
      vv[0]=ca.x; vv[1]=ca.y; vv[2]=ca.z; vv[3]=ca.w;
      vv[4]=cb.x; vv[5]=cb.y; vv[6]=cb.z; vv[7]=cb.w;
    }
    half8 hv;
#pragma unroll
    for (int j=0;j<8;j++) hv[j] = (_Float16)vv[j];
    return hv;
  };
  auto writeLDS = [&](int p, half8 hv){
    int pr = p*64 + rr8;
    *(half8*)&Us[(size_t)pr*64 + ((hq ^ (pr&7))<<3)] = hv;
  };

  bool p2 = (passes >= 2), p3 = (passes >= 3), p4 = (passes >= 4);
  half8 f0{}, f1{}, f2{}, f3{};

  f32x16 acc0={}, acc1={};
  f0 = loadPass(0,0);
  if (p2) f1 = loadPass(0,1);
  if (p3) f2 = loadPass(0,2);
  if (p4) f3 = loadPass(0,3);
  for (int t=0; t<nch; ++t){
    asm volatile("s_waitcnt lgkmcnt(0)" ::: "memory");
    __builtin_amdgcn_s_barrier();
    writeLDS(0,f0);
    if (p2) writeLDS(1,f1);
    if (p3) writeLDS(2,f2);
    if (p4) writeLDS(3,f3);
    if (t+1 < nch){
      f0 = loadPass(t+1,0);
      if (p2) f1 = loadPass(t+1,1);
      if (p3) f2 = loadPass(t+1,2);
      if (p4) f3 = loadPass(t+1,3);
    }
    asm volatile("s_waitcnt lgkmcnt(0)" ::: "memory");
    __builtin_amdgcn_s_barrier();
    if (active){
#pragma unroll
      for (int st=0; st<4; ++st){
        int u = st*2 + uo;
        half8 a0 = *(const half8*)&Us[(size_t)r0*64 + ((u^(r0&7))<<3)];
        half8 a1 = *(const half8*)&Us[(size_t)r1*64 + ((u^(r1&7))<<3)];
        half8 bb = *(const half8*)&Us[(size_t)cr*64 + ((u^(cr&7))<<3)];
        acc0 = __builtin_amdgcn_mfma_f32_32x32x16_f16(a0,bb,acc0,0,0,0);
        acc1 = __builtin_amdgcn_mfma_f32_32x32x16_f16(a1,bb,acc1,0,0,0);
      }
    }
  }
  if (active){
    size_t off = (size_t)bs*1114112 + pairbase[pair] + (size_t)slotIdx*tsz[pair];
    float* pp = (off < 4194304) ? (dpart + off) : (wpart + (off - 4194304));
    int cp = (pair<3)?128:64;
    int rr = 4*uo, cc = lane&31;
#pragma unroll
    for (int reg=0;reg<16;reg++){
      int ro = (reg&3) + 8*(reg>>2) + rr;
      pp[(size_t)(rbase+ro)*cp + cbase+cc]    = acc0[reg];
      pp[(size_t)(rbase+32+ro)*cp + cbase+cc] = acc1[reg];
    }
  }
}

// ---------- reduce partials -> P (both triangles) ----------
__global__ __launch_bounds__(256) void reduce_kernel(const float* __restrict__ dpart,
    const float* __restrict__ wpart, float* __restrict__ P){
  const int PAarr[6]={0,0,1,0,1,2}, PBarr[6]={0,1,1,2,2,2};
  const int pairbase[6]={0,262144,524288,786432,917504,1048576};
  const int tsz[6]={16384,16384,16384,8192,8192,4096};
  const int chunkbase[7]={0,16,32,48,56,64,68};
  int chunk = blockIdx.x, bs = blockIdx.y;
  int pair = 0;
  while (chunk >= chunkbase[pair+1]) pair++;
  int lc = chunk - chunkbase[pair];
  int CN = (pair<3)?128:64;
  int Roff = PAarr[pair]*128, Coff = PBarr[pair]*128;
  int csh = (CN==128)?7:6;
  int cell0 = lc*1024 + threadIdx.x*4;
  int r = cell0 >> csh, c = cell0 & (CN-1);
  float4 v = make_float4(0.f,0.f,0.f,0.f);
  size_t base = (size_t)bs*1114112 + pairbase[pair];
  for (int k=0;k<16;k++){
    size_t off = base + (size_t)k*tsz[pair];
    const float* pp = (off < 4194304) ? (dpart + off) : (wpart + (off - 4194304));
    float4 t = *(const float4*)&pp[(size_t)r*CN + c];
    v.x += t.x; v.y += t.y; v.z += t.z; v.w += t.w;
  }
  float* Pb = P + (size_t)bs*102400;
  *(float4*)&Pb[(size_t)(Roff+r)*320 + Coff+c] = v;
  Pb[(size_t)(Coff+c  )*320 + Roff+r] = v.x;
  Pb[(size_t)(Coff+c+1)*320 + Roff+r] = v.y;
  Pb[(size_t)(Coff+c+2)*320 + Roff+r] = v.z;
  Pb[(size_t)(Coff+c+3)*320 + Roff+r] = v.w;
}

// ---------- kw transpose ----------
__global__ __launch_bounds__(256) void kwT_kernel(const float* __restrict__ kw, float* __restrict__ kwT){
  int idx = blockIdx.x*256 + threadIdx.x;
  if (idx >= 2*KDIM*KDIM) return;
  int s = idx / (KDIM*KDIM);
  int r = idx - s*KDIM*KDIM;
  int k = r / KDIM, j = r - k*KDIM;
  kwT[(size_t)s*KDIM*KDIM + (size_t)j*KDIM + k] = kw[idx];
}

// ---------- fused V row + key-norm accumulation ----------
__global__ __launch_bounds__(256) void vknorm_kernel(const float* __restrict__ P,
    const float* __restrict__ kwT, float* __restrict__ kn){
  int j = blockIdx.x, bs = blockIdx.y;
  int s = bs & 1;
  __shared__ float prow[KDIM];
  const float* Pb = P + (size_t)bs*102400 + (size_t)j*320;
  for (int i=threadIdx.x;i<KDIM;i+=256) prow[i]=Pb[i];
  __syncthreads();
  const float* kt = kwT + (size_t)s*KDIM*KDIM;
  int k = threadIdx.x;
  float acc=0.f;
  for (int jp=0;jp<KDIM;jp++) acc = fmaf(prow[jp], kt[(size_t)jp*KDIM + k], acc);
  atomicAdd(&kn[bs*256 + k], kt[(size_t)j*KDIM + k] * acc);
}

// ---------- w row + inorm partial stats ----------
__global__ __launch_bounds__(256) void wmat_kernel(const float* __restrict__ P,
    const float* __restrict__ kwT, const float* __restrict__ kn,
    float* __restrict__ wbuf, float* __restrict__ wstats){
  int bs = blockIdx.x >> 5, c = blockIdx.x & 31;
  int s = bs & 1;
  __shared__ float prow[KDIM];
  const float* PbB = P + (size_t)bs*102400;
  const float* Pb = PbB + (size_t)(288+c)*320;
  for (int i=threadIdx.x;i<KDIM;i+=256) prow[i]=Pb[i];
  __syncthreads();
  const float* kt = kwT + (size_t)s*KDIM*KDIM;
  int k = threadIdx.x;
  float acc=0.f;
  for (int j=0;j<KDIM;j++) acc = fmaf(prow[j], kt[(size_t)j*KDIM + k], acc);
  float rk = 1.f/fmaxf(sqrtf(fmaxf(kn[bs*256+k],0.f)),1e-12f);
  float qn = PbB[(size_t)(288+c)*320 + 288+c];
  float rq = 1.f/fmaxf(sqrtf(fmaxf(qn,0.f)),1e-12f);
  float wv = acc * rq * rk * (1.f/128.f);
  wbuf[((size_t)bs*32 + c)*256 + k] = wv;
  __shared__ float red[8];
  float r1 = warp_rsum(wv), r2 = warp_rsum(wv*wv);
  int lane = threadIdx.x & 63, wid = threadIdx.x >> 6;
  if (lane==0){ red[wid]=r1; red[4+wid]=r2; }
  __syncthreads();
  if (threadIdx.x==0){
    atomicAdd(&wstats[bs*2],   red[0]+red[1]+red[2]+red[3]);
    atomicAdd(&wstats[bs*2+1], red[4]+red[5]+red[6]+red[7]);
  }
}

// ---------- inorm + softmax + tap-fragment pack ----------
__global__ __launch_bounds__(256) void smxtswf_kernel(const float* __restrict__ wbuf,
    const float* __restrict__ wstats, _Float16* __restrict__ tswf){
  int bs = blockIdx.x >> 5, c = blockIdx.x & 31;
  float s1 = wstats[bs*2], s2 = wstats[bs*2+1];
  const float N = 8192.f;
  float m = s1/N, var = s2/N - m*m;
  float rs = rsqrtf(var + 1e-5f);
  int k = threadIdx.x;
  float v = (wbuf[((size_t)bs*32 + c)*256 + k] - m)*rs;
  __shared__ float red[4];
  __shared__ float sm[256];
  __shared__ float cs[32];
  float mx = warp_rmax(v);
  int lane = k & 63, wid = k >> 6;
  if (lane==0) red[wid]=mx;
  __syncthreads();
  float MX = fmaxf(fmaxf(red[0],red[1]),fmaxf(red[2],red[3]));
  __syncthreads();
  float e = expf(v - MX);
  float es = warp_rsum(e);
  if (lane==0) red[wid]=es;
  __syncthreads();
  float ES = red[0]+red[1]+red[2]+red[3];
  sm[k] = e/ES;
  __syncthreads();
  if (k < 32){
    float a = 0.f;
#pragma unroll
    for (int l=0;l<8;l++) a += sm[l*32+k];
    cs[k] = a;
  }
  __syncthreads();
  if (k < 36){
    int ks = k >> 1;
    int hi = k & 1;
    int ln = c + (hi<<5);
    half8 hv;
#pragma unroll
    for (int j=0;j<8;j++){
      int ki = ks*16 + (hi<<3) + j;
      int t = ki >> 5, ch = ki & 31;
      float vv = (t==0) ? cs[ch] : -sm[(t-1)*32 + ch];
      hv[j] = (_Float16)vv;
    }
    *(half8*)&tswf[((size_t)(bs*18 + ks)*64 + ln)*8] = hv;
  }
}

// ---------- attention apply as MFMA GEMM ----------
__global__ __launch_bounds__(256,2) void attn_mfma_kernel(const float* __restrict__ y,
    const _Float16* __restrict__ tswf, float* __restrict__ outs){
  int blk = blockIdx.x;
  int w = blk & 127;
  int s = (blk >> 7) & 1;
  int b = blk >> 8;
  int bs = b*SS + s;
  int dil = 1 + s;
  __shared__ __align__(16) _Float16 ybuf[3*132*YPITCH];
  const float* yb = y + ((size_t)bs*HCC)*AREA_;
  int tid = threadIdx.x;
  int lane = tid & 63, wid = tid >> 6;

  const _Float16* tf = tswf + ((size_t)bs*18*64 + lane)*8;
  half8 afr[18];
#pragma unroll
  for (int ks=0; ks<18; ++ks) afr[ks] = *(const half8*)&tf[(size_t)ks*64*8];

  for (int i = tid; i < 384; i += 256){
    int ch = i & 31;
    int q = i >> 5;
    int wr = q >> 2, hb = q & 3;
    int hi = (hb < 2) ? hb : (128 + hb);
    int oct = (ch>>3) ^ ((hi>>2)&3);
    ybuf[(size_t)(wr*132+hi)*YPITCH + oct*8 + (ch&7)] = (_Float16)0.f;
  }
  int ch8 = tid >> 5;
  int h4 = (tid & 31) * 4;
#pragma unroll
  for (int r = 0; r < 12; ++r){
    int wr = r >> 2, chg = r & 3;
    int wy = w + (wr-1)*dil;
    if (wy < 0 || wy >= 128) continue;
    int ch = chg*8 + ch8;
    float4 v = *(const float4*)&yb[(size_t)ch*AREA_ + wy*128 + h4];
    float vv[4] = {v.x, v.y, v.z, v.w};
#pragma unroll
    for (int j=0;j<4;j++){
      int hi = h4 + 2 + j;
      int oct = (ch>>3) ^ ((hi>>2)&3);
      ybuf[(size_t)(wr*132+hi)*YPITCH + oct*8 + (ch&7)] = (_Float16)vv[j];
    }
  }
  __syncthreads();

  const int offy[9]={0,-1,-1,-1,0,1,1,1,0};
  const int offx[9]={0,-1,0,1,1,1,0,-1,-1};
  int n0 = wid * 32;
  int nl = n0 + (lane & 31);
  int ko = lane >> 5;
  f32x16 acc = {};
#pragma unroll
  for (int ks=0; ks<18; ++ks){
    int t = ks >> 1;
    int wy = w + offy[t]*dil;
    half8 bfr = {};
    if (wy >= 0 && wy < 128){
      int wr = offy[t] + 1;
      int hi = nl + offx[t]*dil + 2;
      int oct = (((ks&1)<<1) | ko) ^ ((hi>>2)&3);
      bfr = *(const half8*)&ybuf[(size_t)(wr*132+hi)*YPITCH + oct*8];
    }
    acc = __builtin_amdgcn_mfma_f32_32x32x16_f16(afr[ks], bfr, acc, 0,0,0);
  }
  float* ob = outs + (size_t)bs*HCC*AREA_ + (size_t)w*128;
  int col = n0 + (lane & 31);
  int rb = 4*(lane>>5);
#pragma unroll
  for (int reg=0; reg<16; ++reg){
    int c = (reg&3) + 8*(reg>>2) + rb;
    ob[(size_t)c*AREA_ + col] = acc[reg];
  }
}

extern "C" void kernel_launch(void* const* d_in, const int* in_sizes, int n_in,
                              void* d_out, int out_size, void* d_ws, size_t ws_size,
                              hipStream_t stream){
  const float* x   = (const float*)d_in[0];
  const float* tw  = (const float*)d_in[1];
  const float* g1  = (const float*)d_in[2];
  const float* b1  = (const float*)d_in[3];
  const float* qw  = (const float*)d_in[4];
  const float* kw  = (const float*)d_in[5];
  const float* ow  = (const float*)d_in[6];
  const float* g2  = (const float*)d_in[7];
  const float* b2  = (const float*)d_in[8];
  float* out = (float*)d_out;
  float* ws = (float*)d_ws;

  float* y      = ws + 64;
  float* qqb    = ws + 4194368;
  float* kwT    = qqb;
  float* wbuf   = ws + 4360256;
  float* wpart  = ws + 8388672;
  float* outs   = wpart;
  float* P      = ws + 13107264;
  float* stats  = ws + 13926464;
  float* wstats = ws + 13926720;
  float* kn     = ws + 13926976;
  _Float16* tswf = (_Float16*)(ws + 13994816);
  float* dpart  = (float*)d_out;
  float* z      = y;

  hipMemsetAsync(stats, 0, 2560*sizeof(float), stream);

  conv_mfma_kernel<<<512,256,0,stream>>>(x, tw, y);
  bn_part_kernel<<<dim3(64,8),256,0,stream>>>(y, stats);
  bnqq_kernel<<<512,256,0,stream>>>(y, stats, g1, b1, qw, y, qqb);
  gram_kernel<<<768,512,0,stream>>>(y, qqb, dpart, wpart);
  reduce_kernel<<<dim3(68,8),256,0,stream>>>(dpart, wpart, P);
  kwT_kernel<<<648,256,0,stream>>>(kw, kwT);
  vknorm_kernel<<<dim3(288,8),256,0,stream>>>(P, kwT, kn);
  wmat_kernel<<<256,256,0,stream>>>(P, kwT, kn, wbuf, wstats);
  smxtswf_kernel<<<256,256,0,stream>>>(wbuf, wstats, tswf);
  attn_mfma_kernel<<<1024,256,0,stream>>>(y, tswf, outs);
  conv_mfma_kernel<<<512,256,0,stream>>>(outs, ow, z);
  bn_part_kernel<<<dim3(64,8),256,0,stream>>>(z, stats+128);
  bn_apply_relu_kernel<<<16384,256,0,stream>>>(z, stats+128, g2, b2, out);
}